// Round 1
// 5405.969 us; speedup vs baseline: 2.3726x; 2.3726x over previous
//
#include <hip/hip_runtime.h>

#define D 256
#define L_TOT 13294

typedef __attribute__((ext_vector_type(8))) __bf16 bf16x8;
typedef __attribute__((ext_vector_type(4))) float f32x4;

__device__ __forceinline__ float bf2f(unsigned short u) {
    return __uint_as_float(((unsigned int)u) << 16);
}
__device__ __forceinline__ unsigned short f2bf(float f) {
    unsigned int u = __float_as_uint(f);
    u += 0x7FFFu + ((u >> 16) & 1u);   // round-to-nearest-even
    return (unsigned short)(u >> 16);
}

// ---------------------------------------------------------------------------
// Dtype probe on level_embed: bf16 data -> ~100% sane exponents; fp32 read as
// halfwords -> ~60%. flag=1 means bf16 inputs.
// ---------------------------------------------------------------------------
__global__ void probe_k(const unsigned short* __restrict__ u, int n, int* __restrict__ flag)
{
    __shared__ int cnt;
    if (threadIdx.x == 0) cnt = 0;
    __syncthreads();
    int c = 0;
    for (int i = threadIdx.x; i < n; i += 256) {
        const int e = (u[i] >> 7) & 0xFF;
        if (e == 0 || (e >= 96 && e <= 150)) ++c;
    }
    atomicAdd(&cnt, c);
    __syncthreads();
    if (threadIdx.x == 0) *flag = (cnt * 10 > n * 9) ? 1 : 0;
}

__global__ __launch_bounds__(256) void convert_k(
    const void* __restrict__ src, unsigned short* __restrict__ dst, int n,
    const int* __restrict__ flag)
{
    const int i = blockIdx.x * 256 + threadIdx.x;
    if (i >= n) return;
    if (*flag) dst[i] = ((const unsigned short*)src)[i];
    else       dst[i] = f2bf(((const float*)src)[i]);
}

// Convert + transpose: src (L,K,N) -> dst (L,N,K) bf16.  Dst-linear (coalesced
// writes); strided reads stay in L2 (weights total ~18 MB fp32). One-time cost.
__global__ __launch_bounds__(256) void convt_k(
    const void* __restrict__ src, unsigned short* __restrict__ dst,
    int K, int N, int L, const int* __restrict__ flag)
{
    const long e = (long)blockIdx.x * 256 + threadIdx.x;
    const long tot = (long)L * K * N;
    if (e >= tot) return;
    const int per = K * N;
    const int li = (int)(e / per);
    const int r  = (int)(e - (long)li * per);
    const int n  = r / K;
    const int k  = r - n * K;
    const long s = (long)li * per + (long)k * N + n;
    dst[e] = (*flag) ? ((const unsigned short*)src)[s]
                     : f2bf(((const float*)src)[s]);
}

// ---------------------------------------------------------------------------
// Flatten (B,D,H,W) src inputs -> state bf16 (tok,D).
// ---------------------------------------------------------------------------
__global__ __launch_bounds__(256) void flatten_k(
    const void* __restrict__ s0, const void* __restrict__ s1,
    const void* __restrict__ s2, const void* __restrict__ s3,
    const int* __restrict__ flag, unsigned short* __restrict__ state)
{
    const long e = (long)blockIdx.x * 256 + threadIdx.x;
    const int d = (int)(e & 255);
    const long tok = e >> 8;
    const int b = (int)(tok / L_TOT);
    const int t = (int)(tok - (long)b * L_TOT);
    const void *sp;
    int hw, idx;
    if (t < 10000)      { sp = s0; hw = 10000; idx = t;          }
    else if (t < 12500) { sp = s1; hw = 2500;  idx = t - 10000;  }
    else if (t < 13125) { sp = s2; hw = 625;   idx = t - 12500;  }
    else                { sp = s3; hw = 169;   idx = t - 13125;  }
    const long a = ((long)b * D + d) * hw + idx;
    state[e] = (*flag) ? ((const unsigned short*)sp)[a]
                       : f2bf(((const float*)sp)[a]);
}

// Per-layer q recompute, fully fused: q = x + pos_input + level_embed (bf16).
__global__ __launch_bounds__(256) void posflat_k(
    const void* __restrict__ p0, const void* __restrict__ p1,
    const void* __restrict__ p2, const void* __restrict__ p3,
    const unsigned short* __restrict__ lev, const int* __restrict__ flag,
    const unsigned short* __restrict__ x, unsigned short* __restrict__ q)
{
    const long e = (long)blockIdx.x * 256 + threadIdx.x;
    const int d = (int)(e & 255);
    const long tok = e >> 8;
    const int b = (int)(tok / L_TOT);
    const int t = (int)(tok - (long)b * L_TOT);
    const void *pp;
    int hw, idx, l;
    if (t < 10000)      { pp = p0; hw = 10000; idx = t;          l = 0; }
    else if (t < 12500) { pp = p1; hw = 2500;  idx = t - 10000;  l = 1; }
    else if (t < 13125) { pp = p2; hw = 625;   idx = t - 12500;  l = 2; }
    else                { pp = p3; hw = 169;   idx = t - 13125;  l = 3; }
    const long a = ((long)b * D + d) * hw + idx;
    const float pv = (*flag) ? bf2f(((const unsigned short*)pp)[a])
                             : ((const float*)pp)[a];
    q[e] = f2bf(pv + bf2f(lev[l * D + d]) + bf2f(x[e]));
}

// ---------------------------------------------------------------------------
// MFMA GEMM: out[M,N] = A[M,K] @ B[K,N] (+bias) (relu) (+resid), bf16 io,
// fp32 MFMA accumulation. B supplied TRANSPOSED: Bt[N][K] row-major (ldB).
// Tile 128x128, BK=64, 256 threads = 4 waves (2x2 of 64x64 each), 4x4 frags
// of mfma_f32_16x16x32_bf16 per wave.
// LDS: As/Bs [128 rows][64 k] bf16, XOR-swizzled in 16B groups:
//   byte(row, grp) = row*128 + (grp ^ (row&7))*16   (G4 fix for 128B rows).
// global_load_lds writes LDS linearly (wave-uniform base + lane*16), so the
// GLOBAL source is pre-swizzled per lane (rule #21: both-sides-or-neither).
// ---------------------------------------------------------------------------
template<bool RELU, bool RESID>
__global__ __launch_bounds__(256, 3) void mgemm_k(
    const unsigned short* __restrict__ A, int ldA,
    const unsigned short* __restrict__ Bt, int ldB,
    const unsigned short* __restrict__ bias,
    const unsigned short* resid,          // no restrict: may alias out (f2b)
    unsigned short* out, int ldOut,
    long M, int K)
{
    __shared__ unsigned short As[128 * 64];
    __shared__ unsigned short Bs[128 * 64];
    const int tid = threadIdx.x;
    const int l  = tid & 63;
    const int w  = tid >> 6;
    const int wm = w >> 1, wn = w & 1;
    const long row0 = (long)blockIdx.x * 128;
    const int  col0 = blockIdx.y * 128;

    f32x4 acc[4][4];
#pragma unroll
    for (int i = 0; i < 4; ++i)
#pragma unroll
        for (int j = 0; j < 4; ++j) acc[i][j] = (f32x4){0.f, 0.f, 0.f, 0.f};

    // staging geometry: round i stages 16B chunk c = i*256+tid:
    //   tile row r = i*32 + (tid>>3), 16B group g = tid&7
    const int sr = tid >> 3;
    const int sg = tid & 7;

    for (int k0 = 0; k0 < K; k0 += 64) {
#pragma unroll
        for (int i = 0; i < 4; ++i) {
            const int r = i * 32 + sr;
            long arow = row0 + r; if (arow >= M) arow = M - 1;   // clamp tail
            const int ke = k0 + ((sg ^ (r & 7)) << 3);           // pre-swizzled src
            const unsigned short* ga = A  + arow * (long)ldA + ke;
            const unsigned short* gb = Bt + (long)(col0 + r) * ldB + ke;
            __builtin_amdgcn_global_load_lds(
                (const __attribute__((address_space(1))) void*)ga,
                (__attribute__((address_space(3))) void*)(As + i * 2048 + w * 512),
                16, 0, 0);
            __builtin_amdgcn_global_load_lds(
                (const __attribute__((address_space(1))) void*)gb,
                (__attribute__((address_space(3))) void*)(Bs + i * 2048 + w * 512),
                16, 0, 0);
        }
        __syncthreads();    // drains vmcnt, tiles ready
#pragma unroll
        for (int ks = 0; ks < 2; ++ks) {
            const int cc  = ks * 4 + (l >> 4);
            const int swz = ((cc ^ (l & 7)) << 4);
            bf16x8 af[4], bfr[4];
#pragma unroll
            for (int mi = 0; mi < 4; ++mi) {
                const int ar = wm * 64 + mi * 16 + (l & 15);
                af[mi] = *(const bf16x8*)((const char*)As + ar * 128 + swz);
            }
#pragma unroll
            for (int ni = 0; ni < 4; ++ni) {
                const int br = wn * 64 + ni * 16 + (l & 15);
                bfr[ni] = *(const bf16x8*)((const char*)Bs + br * 128 + swz);
            }
#pragma unroll
            for (int mi = 0; mi < 4; ++mi)
#pragma unroll
                for (int ni = 0; ni < 4; ++ni)
                    acc[mi][ni] = __builtin_amdgcn_mfma_f32_16x16x32_bf16(
                        af[mi], bfr[ni], acc[mi][ni], 0, 0, 0);
        }
        __syncthreads();    // compute done before next stage overwrites
    }

    // epilogue: C/D layout col=lane&15, row=(lane>>4)*4+r  [m89/m91]
#pragma unroll
    for (int ni = 0; ni < 4; ++ni) {
        const int col = col0 + wn * 64 + ni * 16 + (l & 15);
        const float bv = bias ? bf2f(bias[col]) : 0.f;
#pragma unroll
        for (int mi = 0; mi < 4; ++mi) {
            const long rbase = row0 + wm * 64 + mi * 16 + (l >> 4) * 4;
#pragma unroll
            for (int r = 0; r < 4; ++r) {
                const long rr = rbase + r;
                if (rr >= M) continue;
                float v = acc[mi][ni][r] + bv;
                if (RELU) v = fmaxf(v, 0.f);
                if (RESID) v += bf2f(resid[rr * (long)ldOut + col]);
                out[rr * (long)ldOut + col] = f2bf(v);
            }
        }
    }
}

// ---------------------------------------------------------------------------
// Deformable sampling: one block per token; thread = (head, channel).
// attn output may alias the q buffer (q dead by now).
// ---------------------------------------------------------------------------
__global__ __launch_bounds__(256) void sample_k(
    const unsigned short* __restrict__ off, const unsigned short* __restrict__ aw,
    const unsigned short* __restrict__ val, unsigned short* __restrict__ attn)
{
    __shared__ float offs[256];
    __shared__ float awv[128];
    __shared__ float hinv[8];
    __shared__ int   cidx[128][4];
    __shared__ float cw[128][4];
    const long tok = blockIdx.x;
    const int tid = threadIdx.x;
    const int b = (int)(tok / L_TOT);
    const int t = (int)(tok - (long)b * L_TOT);
    offs[tid] = bf2f(off[tok * 256 + tid]);
    if (tid < 128) awv[tid] = bf2f(aw[tok * 128 + tid]);
    __syncthreads();
    if (tid < 8) {
        float m = -1e30f;
        for (int j = 0; j < 16; ++j) m = fmaxf(m, awv[tid * 16 + j]);
        float s = 0.f;
        for (int j = 0; j < 16; ++j) {
            const float e = expf(awv[tid * 16 + j] - m);
            awv[tid * 16 + j] = e; s += e;
        }
        hinv[tid] = 1.f / s;
    }
    __syncthreads();
    int st0, W0;
    if (t < 10000)      { st0 = 0;     W0 = 100; }
    else if (t < 12500) { st0 = 10000; W0 = 50;  }
    else if (t < 13125) { st0 = 12500; W0 = 25;  }
    else                { st0 = 13125; W0 = 13;  }
    const int i0 = t - st0;
    const int yy = i0 / W0;
    const int xx = i0 - yy * W0;
    const float gx = (xx + 0.5f) / (float)W0;
    const float gy = (yy + 0.5f) / (float)W0;   // square levels
    if (tid < 128) {
        const int u = tid;
        const int l = (u >> 2) & 3;
        const int Wv  = (l == 0) ? 100 : (l == 1) ? 50 : (l == 2) ? 25 : 13;
        const int stl = (l == 0) ? 0 : (l == 1) ? 10000 : (l == 2) ? 12500 : 13125;
        const float ox = offs[2 * u], oy = offs[2 * u + 1];
        const float px = (gx + ox / (float)Wv) * Wv - 0.5f;
        const float py = (gy + oy / (float)Wv) * Wv - 0.5f;
        const float fx = floorf(px), fy = floorf(py);
        const float wx1 = px - fx, wy1 = py - fy;
        const int x0 = (int)fx, y0 = (int)fy;
        const float a = awv[u] * hinv[u >> 4];
#pragma unroll
        for (int c = 0; c < 4; ++c) {
            const int xi = x0 + (c & 1);
            const int yi = y0 + (c >> 1);
            const float wgt = ((c & 1) ? wx1 : 1.f - wx1) * ((c >> 1) ? wy1 : 1.f - wy1);
            const bool ok = (xi >= 0) && (xi < Wv) && (yi >= 0) && (yi < Wv);
            cidx[u][c] = ok ? (stl + yi * Wv + xi) : 0;
            cw[u][c]   = ok ? wgt * a : 0.f;
        }
    }
    __syncthreads();
    const int h = tid >> 5, dch = tid & 31;
    const unsigned short* vb = val + ((long)b * L_TOT) * 256 + h * 32 + dch;
    float o = 0.f;
    for (int lp = 0; lp < 16; ++lp) {
        const int u = h * 16 + lp;
#pragma unroll
        for (int c = 0; c < 4; ++c) {
            const float w = cw[u][c];
            if (w != 0.f)
                o = fmaf(w, bf2f(vb[(long)cidx[u][c] * 256]), o);
        }
    }
    __syncthreads();   // all LDS consumers done before attn overwrites q
    attn[tok * 256 + tid] = f2bf(o);
}

// ---------------------------------------------------------------------------
// LayerNorm over D=256. Block = 4 waves = 4 tokens; lane = 4 channels.
// ---------------------------------------------------------------------------
__global__ __launch_bounds__(256) void ln_k(
    const unsigned short* __restrict__ y,
    const unsigned short* __restrict__ g, const unsigned short* __restrict__ bb,
    unsigned short* __restrict__ out, long nt)
{
    const int wv = threadIdx.x >> 6;
    const int lane = threadIdx.x & 63;
    const long tok = (long)blockIdx.x * 4 + wv;
    if (tok >= nt) return;
    const ushort4 v4 = *(const ushort4*)(y + tok * D + lane * 4);
    const float v0 = bf2f(v4.x), v1 = bf2f(v4.y), v2 = bf2f(v4.z), v3 = bf2f(v4.w);
    float s = v0 + v1 + v2 + v3;
#pragma unroll
    for (int m = 1; m < 64; m <<= 1) s += __shfl_xor(s, m);
    const float mean = s * (1.f / D);
    const float d0 = v0 - mean, d1 = v1 - mean, d2 = v2 - mean, d3 = v3 - mean;
    float q = d0 * d0 + d1 * d1 + d2 * d2 + d3 * d3;
#pragma unroll
    for (int m = 1; m < 64; m <<= 1) q += __shfl_xor(q, m);
    const float rstd = rsqrtf(q * (1.f / D) + 1e-5f);
    const int c0 = lane * 4;
    ushort4 o;
    o.x = f2bf(d0 * rstd * bf2f(g[c0 + 0]) + bf2f(bb[c0 + 0]));
    o.y = f2bf(d1 * rstd * bf2f(g[c0 + 1]) + bf2f(bb[c0 + 1]));
    o.z = f2bf(d2 * rstd * bf2f(g[c0 + 2]) + bf2f(bb[c0 + 2]));
    o.w = f2bf(d3 * rstd * bf2f(g[c0 + 3]) + bf2f(bb[c0 + 3]));
    *(ushort4*)(out + tok * D + lane * 4) = o;
}

// ---------------------------------------------------------------------------
// Finalize: OUTPUT IS FP32. d_out[0, osz-4) = final src (bf16 state -> f32);
// d_out[osz-4, osz) = level_start_index as f32.
// ---------------------------------------------------------------------------
__global__ __launch_bounds__(256) void finalize_k(
    const unsigned short* __restrict__ state, float* __restrict__ out, long osz)
{
    const long e = (long)blockIdx.x * 256 + threadIdx.x;
    const long n0 = osz - 4;
    if (e < n0) out[e] = bf2f(state[e]);
    if (e < 4) {
        const float st[4] = {0.f, 10000.f, 12500.f, 13125.f};
        out[n0 + e] = st[e];
    }
}

extern "C" void kernel_launch(void* const* d_in, const int* in_sizes, int n_in,
                              void* d_out, int out_size, void* d_ws, size_t ws_size,
                              hipStream_t stream)
{
    (void)n_in; (void)ws_size;
    const long osz = (long)out_size;
    const long nt = (osz - 4) / D;                      // total tokens
    const int nlayers = in_sizes[9] / (D * D);          // so_w: (NL, 256, 256)
    const int dff = in_sizes[19] / (nlayers * D);       // f1_w: (NL, 256, DFF)

    char* ws = (char*)d_ws;
    int* flag = (int*)ws;  ws += 256;
    unsigned short* wc = (unsigned short*)ws;           // canonical bf16 weights
    long off[25]; long acc_off = 0;
    for (int i = 8; i <= 24; ++i) { off[i] = acc_off; acc_off += in_sizes[i]; }
    ws += ((acc_off * 2 + 255) / 256) * 256;
    const size_t SZ_BF = (size_t)nt * D * 2;
    unsigned short* state     = (unsigned short*)ws;  ws += SZ_BF;  // running src (bf16)
    unsigned short* val_b     = (unsigned short*)ws;  ws += SZ_BF;  // value / h[:,0:256]
    unsigned short* offy_b    = (unsigned short*)ws;  ws += SZ_BF;  // offsets, y / h[:,256:512]
    unsigned short* posattn_b = (unsigned short*)ws;  ws += SZ_BF;  // q, then attn, then ffn-partial
    unsigned short* aw_b      = (unsigned short*)ws;  ws += (size_t)nt * 128 * 2;
    unsigned short* hbuf = val_b;   // [nt][dff/2] spans val_b..offy_b (contiguous)
    // total unchanged (~131.5 MB @ B=4)

    probe_k<<<1, 256, 0, stream>>>((const unsigned short*)d_in[8], in_sizes[8], flag);

    // vectors/biases: plain convert
    const int vecIdx[11] = {8, 10, 12, 14, 16, 17, 18, 20, 22, 23, 24};
    for (int j = 0; j < 11; ++j) {
        const int i = vecIdx[j];
        convert_k<<<(in_sizes[i] + 255) / 256, 256, 0, stream>>>(
            d_in[i], wc + off[i], in_sizes[i], flag);
    }
    // matrices: convert + transpose to [N][K] for MFMA B-fragments
    const int matIdx[6] = {9, 11, 13, 15, 19, 21};
    const int matK[6]   = {D, D, D, D, D, dff};
    const int matN[6]   = {D, 128, D, D, dff, D};
    for (int j = 0; j < 6; ++j) {
        const int i = matIdx[j];
        convt_k<<<(in_sizes[i] + 255) / 256, 256, 0, stream>>>(
            d_in[i], wc + off[i], matK[j], matN[j], nlayers, flag);
    }

    flatten_k<<<(int)nt, 256, 0, stream>>>(
        d_in[0], d_in[2], d_in[4], d_in[6], flag, state);

    const int MB = (int)((nt + 127) / 128);
    const int LB = (int)((nt + 3) / 4);
    const int dh = dff / 2;                     // 512: FFN split so h fits 2 buffers

    for (int i = 0; i < nlayers; ++i) {
        posflat_k<<<(int)nt, 256, 0, stream>>>(                 // q = x+pos+lev
            d_in[1], d_in[3], d_in[5], d_in[7], wc + off[8], flag, state, posattn_b);
        mgemm_k<false, false><<<dim3(MB, 2), 256, 0, stream>>>( // value = x@Wv+bv
            state, D, wc + off[13] + (long)i * D * D, D, wc + off[14] + i * D,
            nullptr, val_b, D, nt, D);
        mgemm_k<false, false><<<dim3(MB, 2), 256, 0, stream>>>( // sampling offsets
            posattn_b, D, wc + off[9] + (long)i * D * 256, D, wc + off[10] + i * 256,
            nullptr, offy_b, D, nt, D);
        mgemm_k<false, false><<<dim3(MB, 1), 256, 0, stream>>>( // attn logits
            posattn_b, D, wc + off[11] + (long)i * D * 128, D, wc + off[12] + i * 128,
            nullptr, aw_b, 128, nt, D);
        sample_k<<<(int)nt, 256, 0, stream>>>(offy_b, aw_b, val_b, posattn_b);
        mgemm_k<false, true><<<dim3(MB, 2), 256, 0, stream>>>(  // out-proj + resid x
            posattn_b, D, wc + off[15] + (long)i * D * D, D, wc + off[16] + i * D,
            state, offy_b, D, nt, D);
        ln_k<<<LB, 256, 0, stream>>>(offy_b, wc + off[17] + i * D, wc + off[18] + i * D,
                                     state, nt);
        // FFN as 2 half-dff passes: partial = x + relu(x@W1a+b1a)@W2a + b2,
        // then partial += relu(x@W1b+b1b)@W2b.  h lives in val_b+offy_b.
        mgemm_k<true, false><<<dim3(MB, dh / 128), 256, 0, stream>>>(
            state, D, wc + off[19] + (long)i * D * dff, D, wc + off[20] + i * dff,
            nullptr, hbuf, dh, nt, D);
        mgemm_k<false, true><<<dim3(MB, 2), 256, 0, stream>>>(
            hbuf, dh, wc + off[21] + (long)i * dff * D, dff, wc + off[22] + i * D,
            state, posattn_b, D, nt, dh);
        mgemm_k<true, false><<<dim3(MB, dh / 128), 256, 0, stream>>>(
            state, D, wc + off[19] + (long)i * D * dff + (long)dh * D, D,
            wc + off[20] + i * dff + dh, nullptr, hbuf, dh, nt, D);
        mgemm_k<false, true><<<dim3(MB, 2), 256, 0, stream>>>(
            hbuf, dh, wc + off[21] + (long)i * dff * D + dh, dff, nullptr,
            posattn_b, posattn_b, D, nt, dh);
        ln_k<<<LB, 256, 0, stream>>>(posattn_b, wc + off[23] + i * D, wc + off[24] + i * D,
                                     state, nt);
    }

    finalize_k<<<(int)((osz - 4 + 255) / 256), 256, 0, stream>>>(
        state, (float*)d_out, osz);
}

// Round 2
// 3053.846 us; speedup vs baseline: 4.2000x; 1.7702x over previous
//
#include <hip/hip_runtime.h>

#define D 256
#define L_TOT 13294

typedef __attribute__((ext_vector_type(8))) __bf16 bf16x8;
typedef __attribute__((ext_vector_type(4))) float f32x4;

__device__ __forceinline__ float bf2f(unsigned short u) {
    return __uint_as_float(((unsigned int)u) << 16);
}
__device__ __forceinline__ unsigned short f2bf(float f) {
    unsigned int u = __float_as_uint(f);
    u += 0x7FFFu + ((u >> 16) & 1u);   // round-to-nearest-even
    return (unsigned short)(u >> 16);
}

// ---------------------------------------------------------------------------
// Dtype probe on level_embed: bf16 data -> ~100% sane exponents; fp32 read as
// halfwords -> ~60%. flag=1 means bf16 inputs.
// ---------------------------------------------------------------------------
__global__ void probe_k(const unsigned short* __restrict__ u, int n, int* __restrict__ flag)
{
    __shared__ int cnt;
    if (threadIdx.x == 0) cnt = 0;
    __syncthreads();
    int c = 0;
    for (int i = threadIdx.x; i < n; i += 256) {
        const int e = (u[i] >> 7) & 0xFF;
        if (e == 0 || (e >= 96 && e <= 150)) ++c;
    }
    atomicAdd(&cnt, c);
    __syncthreads();
    if (threadIdx.x == 0) *flag = (cnt * 10 > n * 9) ? 1 : 0;
}

__global__ __launch_bounds__(256) void convert_k(
    const void* __restrict__ src, unsigned short* __restrict__ dst, int n,
    const int* __restrict__ flag)
{
    const int i = blockIdx.x * 256 + threadIdx.x;
    if (i >= n) return;
    if (*flag) dst[i] = ((const unsigned short*)src)[i];
    else       dst[i] = f2bf(((const float*)src)[i]);
}

// Convert + transpose: src (L,K,N) -> dst (L,N,K) bf16.  Dst-linear (coalesced
// writes); strided reads stay in L2 (weights total ~18 MB fp32). One-time cost.
__global__ __launch_bounds__(256) void convt_k(
    const void* __restrict__ src, unsigned short* __restrict__ dst,
    int K, int N, int L, const int* __restrict__ flag)
{
    const long e = (long)blockIdx.x * 256 + threadIdx.x;
    const long tot = (long)L * K * N;
    if (e >= tot) return;
    const int per = K * N;
    const int li = (int)(e / per);
    const int r  = (int)(e - (long)li * per);
    const int n  = r / K;
    const int k  = r - n * K;
    const long s = (long)li * per + (long)k * N + n;
    dst[e] = (*flag) ? ((const unsigned short*)src)[s]
                     : f2bf(((const float*)src)[s]);
}

// ---------------------------------------------------------------------------
// Flatten (B,D,H,W) src inputs -> state bf16 (tok,D).
// ---------------------------------------------------------------------------
__global__ __launch_bounds__(256) void flatten_k(
    const void* __restrict__ s0, const void* __restrict__ s1,
    const void* __restrict__ s2, const void* __restrict__ s3,
    const int* __restrict__ flag, unsigned short* __restrict__ state)
{
    const long e = (long)blockIdx.x * 256 + threadIdx.x;
    const int d = (int)(e & 255);
    const long tok = e >> 8;
    const int b = (int)(tok / L_TOT);
    const int t = (int)(tok - (long)b * L_TOT);
    const void *sp;
    int hw, idx;
    if (t < 10000)      { sp = s0; hw = 10000; idx = t;          }
    else if (t < 12500) { sp = s1; hw = 2500;  idx = t - 10000;  }
    else if (t < 13125) { sp = s2; hw = 625;   idx = t - 12500;  }
    else                { sp = s3; hw = 169;   idx = t - 13125;  }
    const long a = ((long)b * D + d) * hw + idx;
    state[e] = (*flag) ? ((const unsigned short*)sp)[a]
                       : f2bf(((const float*)sp)[a]);
}

// Per-layer q recompute, fully fused: q = x + pos_input + level_embed (bf16).
__global__ __launch_bounds__(256) void posflat_k(
    const void* __restrict__ p0, const void* __restrict__ p1,
    const void* __restrict__ p2, const void* __restrict__ p3,
    const unsigned short* __restrict__ lev, const int* __restrict__ flag,
    const unsigned short* __restrict__ x, unsigned short* __restrict__ q)
{
    const long e = (long)blockIdx.x * 256 + threadIdx.x;
    const int d = (int)(e & 255);
    const long tok = e >> 8;
    const int b = (int)(tok / L_TOT);
    const int t = (int)(tok - (long)b * L_TOT);
    const void *pp;
    int hw, idx, l;
    if (t < 10000)      { pp = p0; hw = 10000; idx = t;          l = 0; }
    else if (t < 12500) { pp = p1; hw = 2500;  idx = t - 10000;  l = 1; }
    else if (t < 13125) { pp = p2; hw = 625;   idx = t - 12500;  l = 2; }
    else                { pp = p3; hw = 169;   idx = t - 13125;  l = 3; }
    const long a = ((long)b * D + d) * hw + idx;
    const float pv = (*flag) ? bf2f(((const unsigned short*)pp)[a])
                             : ((const float*)pp)[a];
    q[e] = f2bf(pv + bf2f(lev[l * D + d]) + bf2f(x[e]));
}

// ---------------------------------------------------------------------------
// MFMA GEMM: out[M,N] = A[M,K] @ B[K,N] (+bias) (relu) (+resid), bf16 io,
// fp32 MFMA accumulation. B supplied TRANSPOSED: Bt[N][K] row-major (ldB).
// Tile 128x128, BK=64, 256 threads = 4 waves (2x2 of 64x64 each), 4x4 frags
// of mfma_f32_16x16x32_bf16 per wave.
// LDS: As/Bs [128 rows][64 k] bf16, XOR-swizzled in 16B groups:
//   byte(row, grp) = row*128 + (grp ^ (row&7))*16   (G4 fix for 128B rows).
// global_load_lds writes LDS linearly (wave-uniform base + lane*16), so the
// GLOBAL source is pre-swizzled per lane (rule #21: both-sides-or-neither).
// ---------------------------------------------------------------------------
template<bool RELU, bool RESID>
__global__ __launch_bounds__(256, 3) void mgemm_k(
    const unsigned short* __restrict__ A, int ldA,
    const unsigned short* __restrict__ Bt, int ldB,
    const unsigned short* __restrict__ bias,
    const unsigned short* resid,          // no restrict: may alias out (f2b)
    unsigned short* out, int ldOut,
    long M, int K)
{
    __shared__ unsigned short As[128 * 64];
    __shared__ unsigned short Bs[128 * 64];
    const int tid = threadIdx.x;
    const int l  = tid & 63;
    const int w  = tid >> 6;
    const int wm = w >> 1, wn = w & 1;
    const long row0 = (long)blockIdx.x * 128;
    const int  col0 = blockIdx.y * 128;

    f32x4 acc[4][4];
#pragma unroll
    for (int i = 0; i < 4; ++i)
#pragma unroll
        for (int j = 0; j < 4; ++j) acc[i][j] = (f32x4){0.f, 0.f, 0.f, 0.f};

    // staging geometry: round i stages 16B chunk c = i*256+tid:
    //   tile row r = i*32 + (tid>>3), 16B group g = tid&7
    const int sr = tid >> 3;
    const int sg = tid & 7;

    for (int k0 = 0; k0 < K; k0 += 64) {
#pragma unroll
        for (int i = 0; i < 4; ++i) {
            const int r = i * 32 + sr;
            long arow = row0 + r; if (arow >= M) arow = M - 1;   // clamp tail
            const int ke = k0 + ((sg ^ (r & 7)) << 3);           // pre-swizzled src
            const unsigned short* ga = A  + arow * (long)ldA + ke;
            const unsigned short* gb = Bt + (long)(col0 + r) * ldB + ke;
            __builtin_amdgcn_global_load_lds(
                (const __attribute__((address_space(1))) void*)ga,
                (__attribute__((address_space(3))) void*)(As + i * 2048 + w * 512),
                16, 0, 0);
            __builtin_amdgcn_global_load_lds(
                (const __attribute__((address_space(1))) void*)gb,
                (__attribute__((address_space(3))) void*)(Bs + i * 2048 + w * 512),
                16, 0, 0);
        }
        __syncthreads();    // drains vmcnt, tiles ready
#pragma unroll
        for (int ks = 0; ks < 2; ++ks) {
            const int cc  = ks * 4 + (l >> 4);
            const int swz = ((cc ^ (l & 7)) << 4);
            bf16x8 af[4], bfr[4];
#pragma unroll
            for (int mi = 0; mi < 4; ++mi) {
                const int ar = wm * 64 + mi * 16 + (l & 15);
                af[mi] = *(const bf16x8*)((const char*)As + ar * 128 + swz);
            }
#pragma unroll
            for (int ni = 0; ni < 4; ++ni) {
                const int br = wn * 64 + ni * 16 + (l & 15);
                bfr[ni] = *(const bf16x8*)((const char*)Bs + br * 128 + swz);
            }
#pragma unroll
            for (int mi = 0; mi < 4; ++mi)
#pragma unroll
                for (int ni = 0; ni < 4; ++ni)
                    acc[mi][ni] = __builtin_amdgcn_mfma_f32_16x16x32_bf16(
                        af[mi], bfr[ni], acc[mi][ni], 0, 0, 0);
        }
        __syncthreads();    // compute done before next stage overwrites
    }

    // epilogue: C/D layout col=lane&15, row=(lane>>4)*4+r  [m89/m91]
#pragma unroll
    for (int ni = 0; ni < 4; ++ni) {
        const int col = col0 + wn * 64 + ni * 16 + (l & 15);
        const float bv = bias ? bf2f(bias[col]) : 0.f;
#pragma unroll
        for (int mi = 0; mi < 4; ++mi) {
            const long rbase = row0 + wm * 64 + mi * 16 + (l >> 4) * 4;
#pragma unroll
            for (int r = 0; r < 4; ++r) {
                const long rr = rbase + r;
                if (rr >= M) continue;
                float v = acc[mi][ni][r] + bv;
                if (RELU) v = fmaxf(v, 0.f);
                if (RESID) v += bf2f(resid[rr * (long)ldOut + col]);
                out[rr * (long)ldOut + col] = f2bf(v);
            }
        }
    }
}

// ---------------------------------------------------------------------------
// Deformable sampling, wide-load version. One block per token.
// Thread = (sample-group g = wave, head h, channel-quad q):
//   tid = g*64 + h*8 + q.  Each lane accumulates 4 channels (ushort4 loads).
// Each wave handles 4 of the 16 samples per head (lp = j*4+g, j=0..3);
// loads are UNCONDITIONAL (index clamped, weight zeroed for OOB) so the 4
// corner loads of a step batch in flight — kills the per-load exec-mask
// serialization of the scalar version (525 us, VALUBusy 36%, both pipes idle).
// Prep tables indexed [lp*8+h] (pad 5) -> per-wave LDS reads hit 8 distinct
// banks (conflict-free); cross-wave reduce via LDS.
// ---------------------------------------------------------------------------
__global__ __launch_bounds__(256) void sample_k(
    const unsigned short* __restrict__ off, const unsigned short* __restrict__ aw,
    const unsigned short* __restrict__ val, unsigned short* __restrict__ attn)
{
    __shared__ float offs[256];
    __shared__ float awv[128];
    __shared__ float hinv[8];
    __shared__ int   cidx[128][5];          // [lp*8+h][corner], pad 5 (banks)
    __shared__ float cw[128][5];
    __shared__ __align__(16) float red[3][64][4];
    const long tok = blockIdx.x;
    const int tid = threadIdx.x;
    const int b = (int)(tok / L_TOT);
    const int t = (int)(tok - (long)b * L_TOT);
    offs[tid] = bf2f(off[tok * 256 + tid]);
    if (tid < 128) awv[tid] = bf2f(aw[tok * 128 + tid]);
    __syncthreads();
    if (tid < 8) {
        float m = -1e30f;
        for (int j = 0; j < 16; ++j) m = fmaxf(m, awv[tid * 16 + j]);
        float s = 0.f;
        for (int j = 0; j < 16; ++j) {
            const float e = expf(awv[tid * 16 + j] - m);
            awv[tid * 16 + j] = e; s += e;
        }
        hinv[tid] = 1.f / s;
    }
    __syncthreads();
    int st0, W0;
    if (t < 10000)      { st0 = 0;     W0 = 100; }
    else if (t < 12500) { st0 = 10000; W0 = 50;  }
    else if (t < 13125) { st0 = 12500; W0 = 25;  }
    else                { st0 = 13125; W0 = 13;  }
    const int i0 = t - st0;
    const int yy = i0 / W0;
    const int xx = i0 - yy * W0;
    const float gx = (xx + 0.5f) / (float)W0;
    const float gy = (yy + 0.5f) / (float)W0;   // square levels
    if (tid < 128) {
        const int u = tid;                       // u = h*16 + lp
        const int mu = (u & 15) * 8 + (u >> 4);  // [lp*8+h]
        const int l = (u >> 2) & 3;
        const int Wv  = (l == 0) ? 100 : (l == 1) ? 50 : (l == 2) ? 25 : 13;
        const int stl = (l == 0) ? 0 : (l == 1) ? 10000 : (l == 2) ? 12500 : 13125;
        const float ox = offs[2 * u], oy = offs[2 * u + 1];
        const float px = (gx + ox / (float)Wv) * Wv - 0.5f;
        const float py = (gy + oy / (float)Wv) * Wv - 0.5f;
        const float fx = floorf(px), fy = floorf(py);
        const float wx1 = px - fx, wy1 = py - fy;
        const int x0 = (int)fx, y0 = (int)fy;
        const float a = awv[u] * hinv[u >> 4];
#pragma unroll
        for (int c = 0; c < 4; ++c) {
            const int xi = x0 + (c & 1);
            const int yi = y0 + (c >> 1);
            const float wgt = ((c & 1) ? wx1 : 1.f - wx1) * ((c >> 1) ? wy1 : 1.f - wy1);
            const bool ok = (xi >= 0) && (xi < Wv) && (yi >= 0) && (yi < Wv);
            cidx[mu][c] = ok ? (stl + yi * Wv + xi) : 0;
            cw[mu][c]   = ok ? wgt * a : 0.f;
        }
    }
    __syncthreads();
    const int g = tid >> 6;                 // sample group (= wave)
    const int l = tid & 63;
    const int h = l >> 3;                   // head
    const int q = l & 7;                    // channel quad
    const unsigned short* vb = val + ((long)b * L_TOT) * 256 + h * 32 + q * 4;
    float a0 = 0.f, a1 = 0.f, a2 = 0.f, a3 = 0.f;
#pragma unroll
    for (int j = 0; j < 4; ++j) {
        const int mu = (j * 4 + g) * 8 + h;
        ushort4 v0 = *(const ushort4*)(vb + (long)cidx[mu][0] * 256);
        ushort4 v1 = *(const ushort4*)(vb + (long)cidx[mu][1] * 256);
        ushort4 v2 = *(const ushort4*)(vb + (long)cidx[mu][2] * 256);
        ushort4 v3 = *(const ushort4*)(vb + (long)cidx[mu][3] * 256);
        const float w0 = cw[mu][0], w1 = cw[mu][1], w2 = cw[mu][2], w3 = cw[mu][3];
        a0 = fmaf(w0, bf2f(v0.x), a0); a1 = fmaf(w0, bf2f(v0.y), a1);
        a2 = fmaf(w0, bf2f(v0.z), a2); a3 = fmaf(w0, bf2f(v0.w), a3);
        a0 = fmaf(w1, bf2f(v1.x), a0); a1 = fmaf(w1, bf2f(v1.y), a1);
        a2 = fmaf(w1, bf2f(v1.z), a2); a3 = fmaf(w1, bf2f(v1.w), a3);
        a0 = fmaf(w2, bf2f(v2.x), a0); a1 = fmaf(w2, bf2f(v2.y), a1);
        a2 = fmaf(w2, bf2f(v2.z), a2); a3 = fmaf(w2, bf2f(v2.w), a3);
        a0 = fmaf(w3, bf2f(v3.x), a0); a1 = fmaf(w3, bf2f(v3.y), a1);
        a2 = fmaf(w3, bf2f(v3.z), a2); a3 = fmaf(w3, bf2f(v3.w), a3);
    }
    if (g) {
        red[g - 1][l][0] = a0; red[g - 1][l][1] = a1;
        red[g - 1][l][2] = a2; red[g - 1][l][3] = a3;
    }
    __syncthreads();
    if (g == 0) {
#pragma unroll
        for (int p = 0; p < 3; ++p) {
            a0 += red[p][l][0]; a1 += red[p][l][1];
            a2 += red[p][l][2]; a3 += red[p][l][3];
        }
        ushort4 o;
        o.x = f2bf(a0); o.y = f2bf(a1); o.z = f2bf(a2); o.w = f2bf(a3);
        *(ushort4*)(attn + tok * 256 + h * 32 + q * 4) = o;
    }
}

// ---------------------------------------------------------------------------
// LayerNorm over D=256. Block = 4 waves = 4 tokens; lane = 4 channels.
// ---------------------------------------------------------------------------
__global__ __launch_bounds__(256) void ln_k(
    const unsigned short* __restrict__ y,
    const unsigned short* __restrict__ g, const unsigned short* __restrict__ bb,
    unsigned short* __restrict__ out, long nt)
{
    const int wv = threadIdx.x >> 6;
    const int lane = threadIdx.x & 63;
    const long tok = (long)blockIdx.x * 4 + wv;
    if (tok >= nt) return;
    const ushort4 v4 = *(const ushort4*)(y + tok * D + lane * 4);
    const float v0 = bf2f(v4.x), v1 = bf2f(v4.y), v2 = bf2f(v4.z), v3 = bf2f(v4.w);
    float s = v0 + v1 + v2 + v3;
#pragma unroll
    for (int m = 1; m < 64; m <<= 1) s += __shfl_xor(s, m);
    const float mean = s * (1.f / D);
    const float d0 = v0 - mean, d1 = v1 - mean, d2 = v2 - mean, d3 = v3 - mean;
    float q = d0 * d0 + d1 * d1 + d2 * d2 + d3 * d3;
#pragma unroll
    for (int m = 1; m < 64; m <<= 1) q += __shfl_xor(q, m);
    const float rstd = rsqrtf(q * (1.f / D) + 1e-5f);
    const int c0 = lane * 4;
    ushort4 o;
    o.x = f2bf(d0 * rstd * bf2f(g[c0 + 0]) + bf2f(bb[c0 + 0]));
    o.y = f2bf(d1 * rstd * bf2f(g[c0 + 1]) + bf2f(bb[c0 + 1]));
    o.z = f2bf(d2 * rstd * bf2f(g[c0 + 2]) + bf2f(bb[c0 + 2]));
    o.w = f2bf(d3 * rstd * bf2f(g[c0 + 3]) + bf2f(bb[c0 + 3]));
    *(ushort4*)(out + tok * D + lane * 4) = o;
}

// ---------------------------------------------------------------------------
// Finalize: OUTPUT IS FP32. d_out[0, osz-4) = final src (bf16 state -> f32);
// d_out[osz-4, osz) = level_start_index as f32.
// ---------------------------------------------------------------------------
__global__ __launch_bounds__(256) void finalize_k(
    const unsigned short* __restrict__ state, float* __restrict__ out, long osz)
{
    const long e = (long)blockIdx.x * 256 + threadIdx.x;
    const long n0 = osz - 4;
    if (e < n0) out[e] = bf2f(state[e]);
    if (e < 4) {
        const float st[4] = {0.f, 10000.f, 12500.f, 13125.f};
        out[n0 + e] = st[e];
    }
}

extern "C" void kernel_launch(void* const* d_in, const int* in_sizes, int n_in,
                              void* d_out, int out_size, void* d_ws, size_t ws_size,
                              hipStream_t stream)
{
    (void)n_in; (void)ws_size;
    const long osz = (long)out_size;
    const long nt = (osz - 4) / D;                      // total tokens
    const int nlayers = in_sizes[9] / (D * D);          // so_w: (NL, 256, 256)
    const int dff = in_sizes[19] / (nlayers * D);       // f1_w: (NL, 256, DFF)

    char* ws = (char*)d_ws;
    int* flag = (int*)ws;  ws += 256;
    unsigned short* wc = (unsigned short*)ws;           // canonical bf16 weights
    long off[25]; long acc_off = 0;
    for (int i = 8; i <= 24; ++i) { off[i] = acc_off; acc_off += in_sizes[i]; }
    ws += ((acc_off * 2 + 255) / 256) * 256;
    const size_t SZ_BF = (size_t)nt * D * 2;
    unsigned short* state     = (unsigned short*)ws;  ws += SZ_BF;  // running src (bf16)
    unsigned short* val_b     = (unsigned short*)ws;  ws += SZ_BF;  // value / h[:,0:256]
    unsigned short* offy_b    = (unsigned short*)ws;  ws += SZ_BF;  // offsets, y / h[:,256:512]
    unsigned short* posattn_b = (unsigned short*)ws;  ws += SZ_BF;  // q, then attn, then ffn-partial
    unsigned short* aw_b      = (unsigned short*)ws;  ws += (size_t)nt * 128 * 2;
    unsigned short* hbuf = val_b;   // [nt][dff/2] spans val_b..offy_b (contiguous)
    // total unchanged (~131.5 MB @ B=4)

    probe_k<<<1, 256, 0, stream>>>((const unsigned short*)d_in[8], in_sizes[8], flag);

    // vectors/biases: plain convert
    const int vecIdx[11] = {8, 10, 12, 14, 16, 17, 18, 20, 22, 23, 24};
    for (int j = 0; j < 11; ++j) {
        const int i = vecIdx[j];
        convert_k<<<(in_sizes[i] + 255) / 256, 256, 0, stream>>>(
            d_in[i], wc + off[i], in_sizes[i], flag);
    }
    // matrices: convert + transpose to [N][K] for MFMA B-fragments
    const int matIdx[6] = {9, 11, 13, 15, 19, 21};
    const int matK[6]   = {D, D, D, D, D, dff};
    const int matN[6]   = {D, 128, D, D, dff, D};
    for (int j = 0; j < 6; ++j) {
        const int i = matIdx[j];
        convt_k<<<(in_sizes[i] + 255) / 256, 256, 0, stream>>>(
            d_in[i], wc + off[i], matK[j], matN[j], nlayers, flag);
    }

    flatten_k<<<(int)nt, 256, 0, stream>>>(
        d_in[0], d_in[2], d_in[4], d_in[6], flag, state);

    const int MB = (int)((nt + 127) / 128);
    const int LB = (int)((nt + 3) / 4);
    const int dh = dff / 2;                     // 512: FFN split so h fits 2 buffers

    for (int i = 0; i < nlayers; ++i) {
        posflat_k<<<(int)nt, 256, 0, stream>>>(                 // q = x+pos+lev
            d_in[1], d_in[3], d_in[5], d_in[7], wc + off[8], flag, state, posattn_b);
        mgemm_k<false, false><<<dim3(MB, 2), 256, 0, stream>>>( // value = x@Wv+bv
            state, D, wc + off[13] + (long)i * D * D, D, wc + off[14] + i * D,
            nullptr, val_b, D, nt, D);
        mgemm_k<false, false><<<dim3(MB, 2), 256, 0, stream>>>( // sampling offsets
            posattn_b, D, wc + off[9] + (long)i * D * 256, D, wc + off[10] + i * 256,
            nullptr, offy_b, D, nt, D);
        mgemm_k<false, false><<<dim3(MB, 1), 256, 0, stream>>>( // attn logits
            posattn_b, D, wc + off[11] + (long)i * D * 128, D, wc + off[12] + i * 128,
            nullptr, aw_b, 128, nt, D);
        sample_k<<<(int)nt, 256, 0, stream>>>(offy_b, aw_b, val_b, posattn_b);
        mgemm_k<false, true><<<dim3(MB, 2), 256, 0, stream>>>(  // out-proj + resid x
            posattn_b, D, wc + off[15] + (long)i * D * D, D, wc + off[16] + i * D,
            state, offy_b, D, nt, D);
        ln_k<<<LB, 256, 0, stream>>>(offy_b, wc + off[17] + i * D, wc + off[18] + i * D,
                                     state, nt);
        // FFN as 2 half-dff passes: partial = x + relu(x@W1a+b1a)@W2a + b2,
        // then partial += relu(x@W1b+b1b)@W2b.  h lives in val_b+offy_b.
        mgemm_k<true, false><<<dim3(MB, dh / 128), 256, 0, stream>>>(
            state, D, wc + off[19] + (long)i * D * dff, D, wc + off[20] + i * dff,
            nullptr, hbuf, dh, nt, D);
        mgemm_k<false, true><<<dim3(MB, 2), 256, 0, stream>>>(
            hbuf, dh, wc + off[21] + (long)i * dff * D, dff, wc + off[22] + i * D,
            state, posattn_b, D, nt, dh);
        mgemm_k<true, false><<<dim3(MB, dh / 128), 256, 0, stream>>>(
            state, D, wc + off[19] + (long)i * D * dff + (long)dh * D, D,
            wc + off[20] + i * dff + dh, nullptr, hbuf, dh, nt, D);
        mgemm_k<false, true><<<dim3(MB, 2), 256, 0, stream>>>(
            hbuf, dh, wc + off[21] + (long)i * dff * D + dh, dff, nullptr,
            posattn_b, posattn_b, D, nt, dh);
        ln_k<<<LB, 256, 0, stream>>>(posattn_b, wc + off[23] + i * D, wc + off[24] + i * D,
                                     state, nt);
    }

    finalize_k<<<(int)((osz - 4 + 255) / 256), 256, 0, stream>>>(
        state, (float*)d_out, osz);
}